// Round 3
// baseline (321.838 us; speedup 1.0000x reference)
//
#include <hip/hip_runtime.h>

typedef unsigned short ushort_t;
typedef __attribute__((ext_vector_type(8))) short bf16x8;
typedef __attribute__((ext_vector_type(4))) short s16x4;
typedef __attribute__((ext_vector_type(4))) float f32x4;

#define BATCH 8
#define SEQ   1024
#define MEMT  8
#define LREAL 1032
#define LPAD  1152   // 9 * 128
#define DMODEL 768
#define NH    12
#define DH    64

// 0.125 * log2(e): Q pre-scaled in GEMM epilogue so attn does exp2(s) directly.
#define CEXP 0.18033688011112042f

__device__ __forceinline__ ushort_t f2b(float x) {
  union { float f; unsigned u; } c; c.f = x;
  unsigned u = c.u;
  unsigned r = (u + 0x7fffu + ((u >> 16) & 1u)) >> 16;
  return (ushort_t)r;
}

#if defined(__has_builtin)
#if __has_builtin(__builtin_amdgcn_global_load_lds)
#define HAVE_GLL 1
#endif
#if __has_builtin(__builtin_amdgcn_exp2f)
#define EXP2F(x) __builtin_amdgcn_exp2f(x)
#endif
#endif
#ifndef EXP2F
#define EXP2F(x) __expf((x) * 0.6931471805599453f)
#endif

__device__ __forceinline__ void stage16(const ushort_t* g, ushort_t* lds_wave_base) {
#ifdef HAVE_GLL
  __builtin_amdgcn_global_load_lds(
      (const __attribute__((address_space(1))) unsigned int*)g,
      (__attribute__((address_space(3))) unsigned int*)lds_wave_base,
      16, 0, 0);
#else
  int lane = threadIdx.x & 63;
  *(bf16x8*)(lds_wave_base + lane * 8) = *(const bf16x8*)g;
#endif
}

// Merged prep (32-bit indexing): blocks [0,6912) build Xm; [6912,8640) cast weights.
__global__ __launch_bounds__(256) void prep(const float* __restrict__ hidden,
                                            const float* __restrict__ memv,
                                            const float* __restrict__ Wq,
                                            const float* __restrict__ Wk,
                                            const float* __restrict__ Wv,
                                            ushort_t* __restrict__ Xm,
                                            ushort_t* __restrict__ Wqb,
                                            ushort_t* __restrict__ Wkb,
                                            ushort_t* __restrict__ Wvb) {
  int bx = blockIdx.x;
  if (bx < 6912) {
    unsigned idx = ((unsigned)bx * 256u + threadIdx.x) * 4u;
    const unsigned perB = (unsigned)LPAD * DMODEL;
    unsigned b = idx / perB;
    unsigned rem = idx - b * perB;
    unsigned row = rem / DMODEL;
    unsigned col = rem - row * DMODEL;
    f32x4 v;
    if (row < SEQ) {
      v = *(const f32x4*)(hidden + ((size_t)b * SEQ + row) * DMODEL + col);
    } else if (row < LREAL) {
      v = *(const f32x4*)(memv + (size_t)(row - SEQ) * DMODEL + col);
    } else {
      v = (f32x4){0.f, 0.f, 0.f, 0.f};
    }
    s16x4 p;
    p[0] = (short)f2b(v[0]); p[1] = (short)f2b(v[1]);
    p[2] = (short)f2b(v[2]); p[3] = (short)f2b(v[3]);
    *(s16x4*)(Xm + idx) = p;
  } else {
    int t = bx - 6912;
    int m = t / 576;
    int i = (t - m * 576) * 256 + threadIdx.x;
    const float* src = m == 0 ? Wq : (m == 1 ? Wk : Wv);
    ushort_t* dst = m == 0 ? Wqb : (m == 1 ? Wkb : Wvb);
    f32x4 v = *(const f32x4*)(src + (size_t)i * 4);
    s16x4 p;
    p[0] = (short)f2b(v[0]); p[1] = (short)f2b(v[1]);
    p[2] = (short)f2b(v[2]); p[3] = (short)f2b(v[3]);
    *(s16x4*)(dst + (size_t)i * 4) = p;
  }
}

// Fused QKV projection, round-3 shape: per-wave 64x64 output (af[4] x bf[4],
// 16 MFMA/iter) to cut LDS fragment traffic per FLOP by 33% (perimeter/area).
// Tiles: Q/K 128x256 (waves 2Mx4N), V 256x128 (waves 4Mx2N) so LPAD=1152 divides.
// Proven 2-phase dbuf __syncthreads pipeline (round-0 structure). BK=32, 24 iters.
// LDS: 2 x 24KB dbuf = 48KB; epilogue image (128x136, 34.8KB) reuses buffer in two
// half-passes -> 3 blocks/CU. 624 blocks, XCD-pinned bijective (8 x 78).
__global__ __launch_bounds__(512, 6) void gemm_fused(
    const ushort_t* __restrict__ Xm,
    const ushort_t* __restrict__ Wqb, const ushort_t* __restrict__ Wkb,
    const ushort_t* __restrict__ Wvb,
    const float* __restrict__ bq, const float* __restrict__ bk,
    const float* __restrict__ bv,
    ushort_t* __restrict__ Qb, ushort_t* __restrict__ Kb,
    ushort_t* __restrict__ Vtb) {
  // buf i at S + i*12288: As @ +0 (BM x 32), Bs @ +BM*32 (BN x 32). BM+BN = 384.
  __shared__ __align__(16) ushort_t S[24576];

  const int tid = threadIdx.x;
  const int wave = tid >> 6, lane = tid & 63;
  const int quad = lane >> 4, l15 = lane & 15;
  const int lrow4 = lane >> 2, lcol8 = (lane & 3) << 3;

  // ---- XCD-pinned bijective decode: 624 = 8 XCD slots x 78 ----
  int bx = blockIdx.x;
  int g = (bx & 7) * 78 + (bx >> 3);
  int task, xt, yt, b;
  if (g < 192) {            // Q: 8 row-tiles(128) x 3 col-tiles(256) x 8 batch
    task = 0; xt = g % 3; int r = g / 3; yt = r & 7; b = r >> 3;
  } else if (g < 408) {     // K: 9 row-tiles(128) x 3 col-tiles(256) x 8 batch
    task = 1; int t = g - 192; xt = t % 3; int r = t / 3; yt = r % 9; b = r / 9;
  } else {                  // V: 3 row-tiles(256, d) x 9 col-tiles(128, tok) x 8
    task = 2; int t = g - 408; xt = t % 9; int r = t / 9; yt = r % 3; b = r / 3;
  }

  const int BM = (task < 2) ? 128 : 256;       // A rows per tile
  const int nA = BM >> 4;                      // A chunks (16 rows each)
  const int bmEl = BM * 32;                    // Bs offset in ushorts
  const int rowTile = (task < 2) ? yt * 128 : yt * 256;
  const int colTile = (task < 2) ? xt * 256 : xt * 128;

  const ushort_t* Xb = Xm + (size_t)b * LPAD * DMODEL;
  const ushort_t* A = task == 2 ? Wvb : Xb;
  const ushort_t* Bsrc = task == 2 ? Xb : (task == 0 ? Wqb : Wkb);
  const float* bias = task == 2 ? bv : (task == 0 ? bq : bk);

  const ushort_t* Abase = A + (size_t)rowTile * DMODEL;
  const ushort_t* Bbase = Bsrc + (size_t)colTile * DMODEL;

  // wave -> 64x64 sub-tile
  int wm, wn, wnCnt;
  if (task < 2) { wm = wave >> 2; wn = wave & 3; wnCnt = 4; }
  else          { wm = wave >> 1; wn = wave & 1; wnCnt = 2; }
  (void)wnCnt;

  // per-wave staging: 3 chunks of 16 rows x 32 cols (c = wave, wave+8, wave+16)
  const ushort_t* sp[3]; int lo[3];
#pragma unroll
  for (int s = 0; s < 3; ++s) {
    int c = wave + s * 8;
    bool isA = c < nA;
    int cb = isA ? c : c - nA;
    sp[s] = (isA ? Abase : Bbase) + (size_t)(cb * 16 + lrow4) * DMODEL + lcol8;
    lo[s] = (isA ? 0 : bmEl) + cb * 512;
  }

  // fragment read offsets (ushort units)
  const int rdA = (wm * 64 + l15) * 32 + quad * 8;           // + mt*512
  const int rdB = bmEl + (wn * 64 + l15) * 32 + quad * 8;    // + nt*512

  f32x4 acc[4][4] = {};

  // prologue: stage tile 0 into buf0
#pragma unroll
  for (int s = 0; s < 3; ++s) stage16(sp[s], S + lo[s]);
  __syncthreads();

  for (int i = 0; i < 24; ++i) {
    ushort_t* cur = S + (i & 1) * 12288;
    if (i < 23) {
      ushort_t* nb = S + ((i + 1) & 1) * 12288;
      int k0 = (i + 1) * 32;
#pragma unroll
      for (int s = 0; s < 3; ++s) stage16(sp[s] + k0, nb + lo[s]);
    }
    bf16x8 af[4], bf[4];
#pragma unroll
    for (int mt = 0; mt < 4; ++mt)
      af[mt] = *(const bf16x8*)&cur[rdA + mt * 512];
#pragma unroll
    for (int nt = 0; nt < 4; ++nt)
      bf[nt] = *(const bf16x8*)&cur[rdB + nt * 512];
#pragma unroll
    for (int mt = 0; mt < 4; ++mt)
#pragma unroll
      for (int nt = 0; nt < 4; ++nt)
        acc[mt][nt] = __builtin_amdgcn_mfma_f32_16x16x32_bf16(af[mt], bf[nt], acc[mt][nt], 0, 0, 0);
    __syncthreads();
  }

  // ---- epilogue: two half-passes through a 128x136 LDS image ----
  const float scale = task == 0 ? CEXP : 1.0f;
#pragma unroll
  for (int h = 0; h < 2; ++h) {
    // participants write their acc quadrant into the image
    bool part = (task < 2) ? ((wn >> 1) == h) : ((wm >> 1) == h);
    if (part) {
#pragma unroll
      for (int mt = 0; mt < 4; ++mt)
#pragma unroll
        for (int nt = 0; nt < 4; ++nt) {
          int ir0, ic;
          float bsv;
          if (task < 2) {
            ir0 = wm * 64 + mt * 16 + quad * 4;              // token-local row
            ic = (wn & 1) * 64 + nt * 16 + l15;              // col within half
            bsv = bias[colTile + h * 128 + ic];
#pragma unroll
            for (int r = 0; r < 4; ++r)
              S[(ir0 + r) * 136 + ic] = f2b((acc[mt][nt][r] + bsv) * scale);
          } else {
            ir0 = (wm & 1) * 64 + mt * 16 + quad * 4;        // d-local row in half
            ic = wn * 64 + nt * 16 + l15;                    // token col
#pragma unroll
            for (int r = 0; r < 4; ++r) {
              bsv = bias[rowTile + h * 128 + ir0 + r];
              S[(ir0 + r) * 136 + ic] = f2b(acc[mt][nt][r] + bsv);
            }
          }
        }
    }
    __syncthreads();

    // cooperative store: 512 threads, image row = tid>>2, 32-col segment each
    {
      int row = tid >> 2;
      int segu = (tid & 3) * 32;
      bf16x8 v0 = *(const bf16x8*)&S[row * 136 + segu + 0];
      bf16x8 v1 = *(const bf16x8*)&S[row * 136 + segu + 8];
      bf16x8 v2 = *(const bf16x8*)&S[row * 136 + segu + 16];
      bf16x8 v3 = *(const bf16x8*)&S[row * 136 + segu + 24];
      if (task == 2) {
        int d = rowTile + h * 128 + row;
        int tok = colTile + segu;
        ushort_t* gp = Vtb + (((size_t)b * NH + (d >> 6)) * DH + (d & 63)) * LPAD + tok;
        *(bf16x8*)(gp + 0) = v0;  *(bf16x8*)(gp + 8) = v1;
        *(bf16x8*)(gp + 16) = v2; *(bf16x8*)(gp + 24) = v3;
      } else {
        ushort_t* out = task == 0 ? Qb : Kb;
        const int Rows = task == 0 ? SEQ : LPAD;
        int colbase = colTile + h * 128 + segu;
        int hd = colbase >> 6, dd = colbase & 63;
        ushort_t* gp = out + (((size_t)b * NH + hd) * Rows + rowTile + row) * DH + dd;
        *(bf16x8*)(gp + 0) = v0;  *(bf16x8*)(gp + 8) = v1;
        *(bf16x8*)(gp + 16) = v2; *(bf16x8*)(gp + 24) = v3;
      }
    }
    if (h == 0) __syncthreads();  // image overwritten by pass 1
  }
}

// Attention: single-barrier prefetch pipeline, 64-key tiles double-buffered (17 tiles,
// fully-padded tile 17 skipped). Block = 128 q rows, 4 waves x 32. Q pre-scaled.
// LDS: KV dbuf 32 KB + Ps 18.4 KB = 51.2 KB -> 3 blocks/CU.
__global__ __launch_bounds__(256, 3) void attn(const ushort_t* __restrict__ Q,
                                               const ushort_t* __restrict__ K,
                                               const ushort_t* __restrict__ Vt,
                                               float* __restrict__ Out) {
  // buf i at KV + i*8192: Ks @ +0 ([kk d-half][key64][32]), Vs @ +4096 ([kc key32][d64][32])
  __shared__ __align__(16) ushort_t KV[16384];
  __shared__ __align__(16) ushort_t Ps[4 * 2304];   // per wave: 32 rows * stride 72

  const int tid = threadIdx.x, wave = tid >> 6, lane = tid & 63;
  const int quad = lane >> 4, l15 = lane & 15;
  const int lrow4 = lane >> 2, lcol8 = (lane & 3) << 3;
  const int bh = blockIdx.x, qt = blockIdx.y;
  const int h = bh % NH, b = bh / NH;

  const ushort_t* Qp = Q + (((size_t)b * NH + h) * SEQ + qt * 128) * DH;
  const ushort_t* Kp = K + ((size_t)b * NH + h) * LPAD * DH;
  const ushort_t* Vp = Vt + ((size_t)b * NH + h) * DH * LPAD;
  ushort_t* Pw = Ps + wave * 2304;

  bf16x8 qf[2][2];
#pragma unroll
  for (int mt = 0; mt < 2; ++mt)
#pragma unroll
    for (int kk = 0; kk < 2; ++kk)
      qf[mt][kk] = *(const bf16x8*)&Qp[(wave * 32 + mt * 16 + l15) * DH + kk * 32 + quad * 8];

  bf16x8 ones8;
#pragma unroll
  for (int j = 0; j < 8; ++j) ones8[j] = (short)0x3f80;

  f32x4 ob[2][4] = {};
  f32x4 obl[2] = {};

  // staging: wave stages K chunks {wave, wave+4}, V chunks {wave, wave+4}
#define STAGE_KV(key0_, buf_)                                                        \
  {                                                                                  \
    _Pragma("unroll")                                                                \
    for (int s = 0; s < 2; ++s) {                                                    \
      int c = wave + s * 4;                                                          \
      int hi = c >> 2, lo = c & 3;                                                   \
      stage16(Kp + (size_t)((key0_) + lo * 16 + lrow4) * DH + hi * 32 + lcol8,       \
              (buf_) + c * 512);                                                     \
      stage16(Vp + (size_t)(lo * 16 + lrow4) * LPAD + (key0_) + hi * 32 + lcol8,     \
              (buf_) + 4096 + c * 512);                                              \
    }                                                                                \
  }

  STAGE_KV(0, KV)
  __syncthreads();

  for (int kt = 0; kt < 17; ++kt) {
    ushort_t* cur = KV + ((kt & 1) << 13);
    if (kt < 16) {
      ushort_t* nxt = KV + (((kt + 1) & 1) << 13);
      STAGE_KV((kt + 1) * 64, nxt)
    }

    // S = Q K^T : 32 q rows x 64 keys per wave
    f32x4 sc[2][4] = {};
#pragma unroll
    for (int kk = 0; kk < 2; ++kk)
#pragma unroll
      for (int nt = 0; nt < 4; ++nt) {
        bf16x8 kf = *(const bf16x8*)&cur[kk * 2048 + (nt * 16 + l15) * 32 + quad * 8];
#pragma unroll
        for (int mt = 0; mt < 2; ++mt)
          sc[mt][nt] = __builtin_amdgcn_mfma_f32_16x16x32_bf16(qf[mt][kk], kf, sc[mt][nt], 0, 0, 0);
      }

    // P = exp2(S) truncated to bf16; mask pad keys (>=1032) on tile 16.
    if (kt < 16) {
#pragma unroll
      for (int mt = 0; mt < 2; ++mt)
#pragma unroll
        for (int nt = 0; nt < 4; ++nt)
#pragma unroll
          for (int r = 0; r < 4; ++r) {
            union { float f; unsigned u; } cu;
            cu.f = EXP2F(sc[mt][nt][r]);
            Pw[(mt * 16 + quad * 4 + r) * 72 + nt * 16 + l15] = (ushort_t)(cu.u >> 16);
          }
    } else {
      bool valid0 = (l15 < 8);  // keys 1024..1031 are nt==0, l15<8
#pragma unroll
      for (int mt = 0; mt < 2; ++mt)
#pragma unroll
        for (int nt = 0; nt < 4; ++nt) {
          bool valid = (nt == 0) && valid0;
#pragma unroll
          for (int r = 0; r < 4; ++r) {
            union { float f; unsigned u; } cu;
            cu.f = valid ? EXP2F(sc[mt][nt][r]) : 0.f;
            Pw[(mt * 16 + quad * 4 + r) * 72 + nt * 16 + l15] = (ushort_t)(cu.u >> 16);
          }
        }
    }

    // O += P V ; l += P 1
#pragma unroll
    for (int kc = 0; kc < 2; ++kc) {
      bf16x8 pf[2];
#pragma unroll
      for (int mt = 0; mt < 2; ++mt)
        pf[mt] = *(const bf16x8*)&Pw[(mt * 16 + l15) * 72 + kc * 32 + quad * 8];
#pragma unroll
      for (int dt = 0; dt < 4; ++dt) {
        bf16x8 vf = *(const bf16x8*)&cur[4096 + kc * 2048 + (dt * 16 + l15) * 32 + quad * 8];
#pragma unroll
        for (int mt = 0; mt < 2; ++mt)
          ob[mt][dt] = __builtin_amdgcn_mfma_f32_16x16x32_bf16(pf[mt], vf, ob[mt][dt], 0, 0, 0);
      }
#pragma unroll
      for (int mt = 0; mt < 2; ++mt)
        obl[mt] = __builtin_amdgcn_mfma_f32_16x16x32_bf16(pf[mt], ones8, obl[mt], 0, 0, 0);
    }
    __syncthreads();
  }

#pragma unroll
  for (int mt = 0; mt < 2; ++mt) {
    int row0 = qt * 128 + wave * 32 + mt * 16 + quad * 4;
    f32x4 linv;
#pragma unroll
    for (int r = 0; r < 4; ++r) linv[r] = 1.0f / obl[mt][r];
#pragma unroll
    for (int dt = 0; dt < 4; ++dt) {
      int col = h * DH + dt * 16 + l15;
#pragma unroll
      for (int r = 0; r < 4; ++r)
        Out[((size_t)b * SEQ + row0 + r) * DMODEL + col] = ob[mt][dt][r] * linv[r];
    }
  }
}

extern "C" void kernel_launch(void* const* d_in, const int* in_sizes, int n_in,
                              void* d_out, int out_size, void* d_ws, size_t ws_size,
                              hipStream_t stream) {
  const float* hidden = (const float*)d_in[0];
  const float* memv   = (const float*)d_in[1];
  const float* Wq = (const float*)d_in[2];
  const float* bq = (const float*)d_in[3];
  const float* Wk = (const float*)d_in[4];
  const float* bk = (const float*)d_in[5];
  const float* Wv = (const float*)d_in[6];
  const float* bv = (const float*)d_in[7];
  float* out = (float*)d_out;

  char* ws = (char*)d_ws;
  size_t off = 0;
  ushort_t* Xm  = (ushort_t*)(ws + off); off += (size_t)BATCH * LPAD * DMODEL * 2;
  ushort_t* Wqb = (ushort_t*)(ws + off); off += (size_t)DMODEL * DMODEL * 2;
  ushort_t* Wkb = (ushort_t*)(ws + off); off += (size_t)DMODEL * DMODEL * 2;
  ushort_t* Wvb = (ushort_t*)(ws + off); off += (size_t)DMODEL * DMODEL * 2;
  ushort_t* Qb  = (ushort_t*)(ws + off); off += (size_t)BATCH * NH * SEQ * DH * 2;
  ushort_t* Kb  = (ushort_t*)(ws + off); off += (size_t)BATCH * NH * LPAD * DH * 2;
  ushort_t* Vtb = (ushort_t*)(ws + off);

  prep<<<dim3(8640), 256, 0, stream>>>(hidden, memv, Wq, Wk, Wv, Xm, Wqb, Wkb, Wvb);
  gemm_fused<<<dim3(624), 512, 0, stream>>>(Xm, Wqb, Wkb, Wvb, bq, bk, bv, Qb, Kb, Vtb);
  attn<<<dim3(96, 8), 256, 0, stream>>>(Qb, Kb, Vtb, out);
}

// Round 4
// 184.980 us; speedup vs baseline: 1.7399x; 1.7399x over previous
//
#include <hip/hip_runtime.h>

typedef unsigned short ushort_t;
typedef __attribute__((ext_vector_type(8))) short bf16x8;
typedef __attribute__((ext_vector_type(4))) short s16x4;
typedef __attribute__((ext_vector_type(4))) float f32x4;

#define BATCH 8
#define SEQ   1024
#define MEMT  8
#define LREAL 1032
#define LPAD  1152   // 9 * 128
#define DMODEL 768
#define NH    12
#define DH    64

// 0.125 * log2(e): Q pre-scaled in GEMM epilogue so attn does exp2(s) directly.
#define CEXP 0.18033688011112042f

__device__ __forceinline__ ushort_t f2b(float x) {
  union { float f; unsigned u; } c; c.f = x;
  unsigned u = c.u;
  unsigned r = (u + 0x7fffu + ((u >> 16) & 1u)) >> 16;
  return (ushort_t)r;
}

#if defined(__has_builtin)
#if __has_builtin(__builtin_amdgcn_global_load_lds)
#define HAVE_GLL 1
#endif
#if __has_builtin(__builtin_amdgcn_exp2f)
#define EXP2F(x) __builtin_amdgcn_exp2f(x)
#endif
#endif
#ifndef EXP2F
#define EXP2F(x) __expf((x) * 0.6931471805599453f)
#endif

__device__ __forceinline__ void stage16(const ushort_t* g, ushort_t* lds_wave_base) {
#ifdef HAVE_GLL
  __builtin_amdgcn_global_load_lds(
      (const __attribute__((address_space(1))) unsigned int*)g,
      (__attribute__((address_space(3))) unsigned int*)lds_wave_base,
      16, 0, 0);
#else
  int lane = threadIdx.x & 63;
  *(bf16x8*)(lds_wave_base + lane * 8) = *(const bf16x8*)g;
#endif
}

// Merged prep (32-bit indexing): blocks [0,6912) build Xm; [6912,8640) cast weights.
__global__ __launch_bounds__(256) void prep(const float* __restrict__ hidden,
                                            const float* __restrict__ memv,
                                            const float* __restrict__ Wq,
                                            const float* __restrict__ Wk,
                                            const float* __restrict__ Wv,
                                            ushort_t* __restrict__ Xm,
                                            ushort_t* __restrict__ Wqb,
                                            ushort_t* __restrict__ Wkb,
                                            ushort_t* __restrict__ Wvb) {
  int bx = blockIdx.x;
  if (bx < 6912) {
    unsigned idx = ((unsigned)bx * 256u + threadIdx.x) * 4u;
    const unsigned perB = (unsigned)LPAD * DMODEL;
    unsigned b = idx / perB;
    unsigned rem = idx - b * perB;
    unsigned row = rem / DMODEL;
    unsigned col = rem - row * DMODEL;
    f32x4 v;
    if (row < SEQ) {
      v = *(const f32x4*)(hidden + ((size_t)b * SEQ + row) * DMODEL + col);
    } else if (row < LREAL) {
      v = *(const f32x4*)(memv + (size_t)(row - SEQ) * DMODEL + col);
    } else {
      v = (f32x4){0.f, 0.f, 0.f, 0.f};
    }
    s16x4 p;
    p[0] = (short)f2b(v[0]); p[1] = (short)f2b(v[1]);
    p[2] = (short)f2b(v[2]); p[3] = (short)f2b(v[3]);
    *(s16x4*)(Xm + idx) = p;
  } else {
    int t = bx - 6912;
    int m = t / 576;
    int i = (t - m * 576) * 256 + threadIdx.x;
    const float* src = m == 0 ? Wq : (m == 1 ? Wk : Wv);
    ushort_t* dst = m == 0 ? Wqb : (m == 1 ? Wkb : Wvb);
    f32x4 v = *(const f32x4*)(src + (size_t)i * 4);
    s16x4 p;
    p[0] = (short)f2b(v[0]); p[1] = (short)f2b(v[1]);
    p[2] = (short)f2b(v[2]); p[3] = (short)f2b(v[3]);
    *(s16x4*)(dst + (size_t)i * 4) = p;
  }
}

// Fused QKV projection: per-wave 64x64 output (af[4] x bf[4], 16 MFMA/iter) to cut
// LDS fragment traffic per FLOP by 33% vs 64x32. Tiles: Q/K 128x256 (waves 2Mx4N),
// V 256x128 (waves 4Mx2N). 2-phase dbuf __syncthreads pipeline. BK=32, 24 iters.
// __launch_bounds__(512,4): 128-reg budget fits 64 AGPR acc + ~60 arch VGPR with
// NO spill (the (512,6) variant forced an ~85-reg budget -> 435 MB of scratch
// writes, 3.5x regression). LDS: 2 x 24KB dbuf = 48KB -> 2 blocks/CU (reg-limited).
// 624 blocks, XCD-pinned bijective (8 x 78).
__global__ __launch_bounds__(512, 4) void gemm_fused(
    const ushort_t* __restrict__ Xm,
    const ushort_t* __restrict__ Wqb, const ushort_t* __restrict__ Wkb,
    const ushort_t* __restrict__ Wvb,
    const float* __restrict__ bq, const float* __restrict__ bk,
    const float* __restrict__ bv,
    ushort_t* __restrict__ Qb, ushort_t* __restrict__ Kb,
    ushort_t* __restrict__ Vtb) {
  // buf i at S + i*12288: As @ +0 (BM x 32), Bs @ +BM*32 (BN x 32). BM+BN = 384.
  __shared__ __align__(16) ushort_t S[24576];

  const int tid = threadIdx.x;
  const int wave = tid >> 6, lane = tid & 63;
  const int quad = lane >> 4, l15 = lane & 15;
  const int lrow4 = lane >> 2, lcol8 = (lane & 3) << 3;

  // ---- XCD-pinned bijective decode: 624 = 8 XCD slots x 78 ----
  int bx = blockIdx.x;
  int g = (bx & 7) * 78 + (bx >> 3);
  int task, xt, yt, b;
  if (g < 192) {            // Q: 8 row-tiles(128) x 3 col-tiles(256) x 8 batch
    task = 0; xt = g % 3; int r = g / 3; yt = r & 7; b = r >> 3;
  } else if (g < 408) {     // K: 9 row-tiles(128) x 3 col-tiles(256) x 8 batch
    task = 1; int t = g - 192; xt = t % 3; int r = t / 3; yt = r % 9; b = r / 9;
  } else {                  // V: 3 row-tiles(256, d) x 9 col-tiles(128, tok) x 8
    task = 2; int t = g - 408; xt = t % 9; int r = t / 9; yt = r % 3; b = r / 3;
  }

  const int BM = (task < 2) ? 128 : 256;       // A rows per tile
  const int nA = BM >> 4;                      // A chunks (16 rows each)
  const int bmEl = BM * 32;                    // Bs offset in ushorts
  const int rowTile = (task < 2) ? yt * 128 : yt * 256;
  const int colTile = (task < 2) ? xt * 256 : xt * 128;

  const ushort_t* Xb = Xm + (size_t)b * LPAD * DMODEL;
  const ushort_t* A = task == 2 ? Wvb : Xb;
  const ushort_t* Bsrc = task == 2 ? Xb : (task == 0 ? Wqb : Wkb);
  const float* bias = task == 2 ? bv : (task == 0 ? bq : bk);

  const ushort_t* Abase = A + (size_t)rowTile * DMODEL;
  const ushort_t* Bbase = Bsrc + (size_t)colTile * DMODEL;

  // wave -> 64x64 sub-tile
  int wm, wn;
  if (task < 2) { wm = wave >> 2; wn = wave & 3; }
  else          { wm = wave >> 1; wn = wave & 1; }

  // per-wave staging: 3 chunks of 16 rows x 32 cols (c = wave, wave+8, wave+16)
  const ushort_t* sp[3]; int lo[3];
#pragma unroll
  for (int s = 0; s < 3; ++s) {
    int c = wave + s * 8;
    bool isA = c < nA;
    int cb = isA ? c : c - nA;
    sp[s] = (isA ? Abase : Bbase) + (size_t)(cb * 16 + lrow4) * DMODEL + lcol8;
    lo[s] = (isA ? 0 : bmEl) + cb * 512;
  }

  // fragment read offsets (ushort units)
  const int rdA = (wm * 64 + l15) * 32 + quad * 8;           // + mt*512
  const int rdB = bmEl + (wn * 64 + l15) * 32 + quad * 8;    // + nt*512

  f32x4 acc[4][4] = {};

  // prologue: stage tile 0 into buf0
#pragma unroll
  for (int s = 0; s < 3; ++s) stage16(sp[s], S + lo[s]);
  __syncthreads();

  for (int i = 0; i < 24; ++i) {
    ushort_t* cur = S + (i & 1) * 12288;
    if (i < 23) {
      ushort_t* nb = S + ((i + 1) & 1) * 12288;
      int k0 = (i + 1) * 32;
#pragma unroll
      for (int s = 0; s < 3; ++s) stage16(sp[s] + k0, nb + lo[s]);
    }
    bf16x8 af[4], bf[4];
#pragma unroll
    for (int mt = 0; mt < 4; ++mt)
      af[mt] = *(const bf16x8*)&cur[rdA + mt * 512];
#pragma unroll
    for (int nt = 0; nt < 4; ++nt)
      bf[nt] = *(const bf16x8*)&cur[rdB + nt * 512];
#pragma unroll
    for (int mt = 0; mt < 4; ++mt)
#pragma unroll
      for (int nt = 0; nt < 4; ++nt)
        acc[mt][nt] = __builtin_amdgcn_mfma_f32_16x16x32_bf16(af[mt], bf[nt], acc[mt][nt], 0, 0, 0);
    __syncthreads();
  }

  // ---- epilogue: two half-passes through a 128x136 LDS image ----
  const float scale = task == 0 ? CEXP : 1.0f;
#pragma unroll
  for (int h = 0; h < 2; ++h) {
    // participants write their acc quadrant into the image
    bool part = (task < 2) ? ((wn >> 1) == h) : ((wm >> 1) == h);
    if (part) {
#pragma unroll
      for (int mt = 0; mt < 4; ++mt)
#pragma unroll
        for (int nt = 0; nt < 4; ++nt) {
          int ir0, ic;
          float bsv;
          if (task < 2) {
            ir0 = wm * 64 + mt * 16 + quad * 4;              // token-local row
            ic = (wn & 1) * 64 + nt * 16 + l15;              // col within half
            bsv = bias[colTile + h * 128 + ic];
#pragma unroll
            for (int r = 0; r < 4; ++r)
              S[(ir0 + r) * 136 + ic] = f2b((acc[mt][nt][r] + bsv) * scale);
          } else {
            ir0 = (wm & 1) * 64 + mt * 16 + quad * 4;        // d-local row in half
            ic = wn * 64 + nt * 16 + l15;                    // token col
#pragma unroll
            for (int r = 0; r < 4; ++r) {
              bsv = bias[rowTile + h * 128 + ir0 + r];
              S[(ir0 + r) * 136 + ic] = f2b(acc[mt][nt][r] + bsv);
            }
          }
        }
    }
    __syncthreads();

    // cooperative store: 512 threads, image row = tid>>2, 32-col segment each
    {
      int row = tid >> 2;
      int segu = (tid & 3) * 32;
      bf16x8 v0 = *(const bf16x8*)&S[row * 136 + segu + 0];
      bf16x8 v1 = *(const bf16x8*)&S[row * 136 + segu + 8];
      bf16x8 v2 = *(const bf16x8*)&S[row * 136 + segu + 16];
      bf16x8 v3 = *(const bf16x8*)&S[row * 136 + segu + 24];
      if (task == 2) {
        int d = rowTile + h * 128 + row;
        int tok = colTile + segu;
        ushort_t* gp = Vtb + (((size_t)b * NH + (d >> 6)) * DH + (d & 63)) * LPAD + tok;
        *(bf16x8*)(gp + 0) = v0;  *(bf16x8*)(gp + 8) = v1;
        *(bf16x8*)(gp + 16) = v2; *(bf16x8*)(gp + 24) = v3;
      } else {
        ushort_t* out = task == 0 ? Qb : Kb;
        const int Rows = task == 0 ? SEQ : LPAD;
        int colbase = colTile + h * 128 + segu;
        int hd = colbase >> 6, dd = colbase & 63;
        ushort_t* gp = out + (((size_t)b * NH + hd) * Rows + rowTile + row) * DH + dd;
        *(bf16x8*)(gp + 0) = v0;  *(bf16x8*)(gp + 8) = v1;
        *(bf16x8*)(gp + 16) = v2; *(bf16x8*)(gp + 24) = v3;
      }
    }
    if (h == 0) __syncthreads();  // image overwritten by pass 1
  }
}

// Attention: single-barrier prefetch pipeline, 64-key tiles double-buffered (17 tiles,
// fully-padded tile 17 skipped). Block = 128 q rows, 4 waves x 32. Q pre-scaled.
// LDS: KV dbuf 32 KB + Ps 18.4 KB = 51.2 KB -> 3 blocks/CU.
__global__ __launch_bounds__(256, 3) void attn(const ushort_t* __restrict__ Q,
                                               const ushort_t* __restrict__ K,
                                               const ushort_t* __restrict__ Vt,
                                               float* __restrict__ Out) {
  // buf i at KV + i*8192: Ks @ +0 ([kk d-half][key64][32]), Vs @ +4096 ([kc key32][d64][32])
  __shared__ __align__(16) ushort_t KV[16384];
  __shared__ __align__(16) ushort_t Ps[4 * 2304];   // per wave: 32 rows * stride 72

  const int tid = threadIdx.x, wave = tid >> 6, lane = tid & 63;
  const int quad = lane >> 4, l15 = lane & 15;
  const int lrow4 = lane >> 2, lcol8 = (lane & 3) << 3;
  const int bh = blockIdx.x, qt = blockIdx.y;
  const int h = bh % NH, b = bh / NH;

  const ushort_t* Qp = Q + (((size_t)b * NH + h) * SEQ + qt * 128) * DH;
  const ushort_t* Kp = K + ((size_t)b * NH + h) * LPAD * DH;
  const ushort_t* Vp = Vt + ((size_t)b * NH + h) * DH * LPAD;
  ushort_t* Pw = Ps + wave * 2304;

  bf16x8 qf[2][2];
#pragma unroll
  for (int mt = 0; mt < 2; ++mt)
#pragma unroll
    for (int kk = 0; kk < 2; ++kk)
      qf[mt][kk] = *(const bf16x8*)&Qp[(wave * 32 + mt * 16 + l15) * DH + kk * 32 + quad * 8];

  bf16x8 ones8;
#pragma unroll
  for (int j = 0; j < 8; ++j) ones8[j] = (short)0x3f80;

  f32x4 ob[2][4] = {};
  f32x4 obl[2] = {};

  // staging: wave stages K chunks {wave, wave+4}, V chunks {wave, wave+4}
#define STAGE_KV(key0_, buf_)                                                        \
  {                                                                                  \
    _Pragma("unroll")                                                                \
    for (int s = 0; s < 2; ++s) {                                                    \
      int c = wave + s * 4;                                                          \
      int hi = c >> 2, lo = c & 3;                                                   \
      stage16(Kp + (size_t)((key0_) + lo * 16 + lrow4) * DH + hi * 32 + lcol8,       \
              (buf_) + c * 512);                                                     \
      stage16(Vp + (size_t)(lo * 16 + lrow4) * LPAD + (key0_) + hi * 32 + lcol8,     \
              (buf_) + 4096 + c * 512);                                              \
    }                                                                                \
  }

  STAGE_KV(0, KV)
  __syncthreads();

  for (int kt = 0; kt < 17; ++kt) {
    ushort_t* cur = KV + ((kt & 1) << 13);
    if (kt < 16) {
      ushort_t* nxt = KV + (((kt + 1) & 1) << 13);
      STAGE_KV((kt + 1) * 64, nxt)
    }

    // S = Q K^T : 32 q rows x 64 keys per wave
    f32x4 sc[2][4] = {};
#pragma unroll
    for (int kk = 0; kk < 2; ++kk)
#pragma unroll
      for (int nt = 0; nt < 4; ++nt) {
        bf16x8 kf = *(const bf16x8*)&cur[kk * 2048 + (nt * 16 + l15) * 32 + quad * 8];
#pragma unroll
        for (int mt = 0; mt < 2; ++mt)
          sc[mt][nt] = __builtin_amdgcn_mfma_f32_16x16x32_bf16(qf[mt][kk], kf, sc[mt][nt], 0, 0, 0);
      }

    // P = exp2(S) truncated to bf16; mask pad keys (>=1032) on tile 16.
    if (kt < 16) {
#pragma unroll
      for (int mt = 0; mt < 2; ++mt)
#pragma unroll
        for (int nt = 0; nt < 4; ++nt)
#pragma unroll
          for (int r = 0; r < 4; ++r) {
            union { float f; unsigned u; } cu;
            cu.f = EXP2F(sc[mt][nt][r]);
            Pw[(mt * 16 + quad * 4 + r) * 72 + nt * 16 + l15] = (ushort_t)(cu.u >> 16);
          }
    } else {
      bool valid0 = (l15 < 8);  // keys 1024..1031 are nt==0, l15<8
#pragma unroll
      for (int mt = 0; mt < 2; ++mt)
#pragma unroll
        for (int nt = 0; nt < 4; ++nt) {
          bool valid = (nt == 0) && valid0;
#pragma unroll
          for (int r = 0; r < 4; ++r) {
            union { float f; unsigned u; } cu;
            cu.f = valid ? EXP2F(sc[mt][nt][r]) : 0.f;
            Pw[(mt * 16 + quad * 4 + r) * 72 + nt * 16 + l15] = (ushort_t)(cu.u >> 16);
          }
        }
    }

    // O += P V ; l += P 1
#pragma unroll
    for (int kc = 0; kc < 2; ++kc) {
      bf16x8 pf[2];
#pragma unroll
      for (int mt = 0; mt < 2; ++mt)
        pf[mt] = *(const bf16x8*)&Pw[(mt * 16 + l15) * 72 + kc * 32 + quad * 8];
#pragma unroll
      for (int dt = 0; dt < 4; ++dt) {
        bf16x8 vf = *(const bf16x8*)&cur[4096 + kc * 2048 + (dt * 16 + l15) * 32 + quad * 8];
#pragma unroll
        for (int mt = 0; mt < 2; ++mt)
          ob[mt][dt] = __builtin_amdgcn_mfma_f32_16x16x32_bf16(pf[mt], vf, ob[mt][dt], 0, 0, 0);
      }
#pragma unroll
      for (int mt = 0; mt < 2; ++mt)
        obl[mt] = __builtin_amdgcn_mfma_f32_16x16x32_bf16(pf[mt], ones8, obl[mt], 0, 0, 0);
    }
    __syncthreads();
  }

#pragma unroll
  for (int mt = 0; mt < 2; ++mt) {
    int row0 = qt * 128 + wave * 32 + mt * 16 + quad * 4;
    f32x4 linv;
#pragma unroll
    for (int r = 0; r < 4; ++r) linv[r] = 1.0f / obl[mt][r];
#pragma unroll
    for (int dt = 0; dt < 4; ++dt) {
      int col = h * DH + dt * 16 + l15;
#pragma unroll
      for (int r = 0; r < 4; ++r)
        Out[((size_t)b * SEQ + row0 + r) * DMODEL + col] = ob[mt][dt][r] * linv[r];
    }
  }
}

extern "C" void kernel_launch(void* const* d_in, const int* in_sizes, int n_in,
                              void* d_out, int out_size, void* d_ws, size_t ws_size,
                              hipStream_t stream) {
  const float* hidden = (const float*)d_in[0];
  const float* memv   = (const float*)d_in[1];
  const float* Wq = (const float*)d_in[2];
  const float* bq = (const float*)d_in[3];
  const float* Wk = (const float*)d_in[4];
  const float* bk = (const float*)d_in[5];
  const float* Wv = (const float*)d_in[6];
  const float* bv = (const float*)d_in[7];
  float* out = (float*)d_out;

  char* ws = (char*)d_ws;
  size_t off = 0;
  ushort_t* Xm  = (ushort_t*)(ws + off); off += (size_t)BATCH * LPAD * DMODEL * 2;
  ushort_t* Wqb = (ushort_t*)(ws + off); off += (size_t)DMODEL * DMODEL * 2;
  ushort_t* Wkb = (ushort_t*)(ws + off); off += (size_t)DMODEL * DMODEL * 2;
  ushort_t* Wvb = (ushort_t*)(ws + off); off += (size_t)DMODEL * DMODEL * 2;
  ushort_t* Qb  = (ushort_t*)(ws + off); off += (size_t)BATCH * NH * SEQ * DH * 2;
  ushort_t* Kb  = (ushort_t*)(ws + off); off += (size_t)BATCH * NH * LPAD * DH * 2;
  ushort_t* Vtb = (ushort_t*)(ws + off);

  prep<<<dim3(8640), 256, 0, stream>>>(hidden, memv, Wq, Wk, Wv, Xm, Wqb, Wkb, Wvb);
  gemm_fused<<<dim3(624), 512, 0, stream>>>(Xm, Wqb, Wkb, Wvb, bq, bk, bv, Qb, Kb, Vtb);
  attn<<<dim3(96, 8), 256, 0, stream>>>(Qb, Kb, Vtb, out);
}